// Round 22
// baseline (80.086 us; speedup 1.0000x reference)
//
#include <hip/hip_runtime.h>
#include <math.h>

#define Hh 96
#define Ww 96
#define HW 9216
#define CIN 64
#define CMID 128
#define NAT_SCALE 11.313708498984761f   // sqrt(128), multiplies logits

typedef __attribute__((ext_vector_type(4))) float f32x4;
typedef __attribute__((ext_vector_type(8))) short short8;

__device__ __forceinline__ unsigned short f2bf(float x) {
    union { float f; unsigned u; } v; v.f = x;
    unsigned r = v.u + 0x7FFF + ((v.u >> 16) & 1);     // RNE
    return (unsigned short)(r >> 16);
}
__device__ __forceinline__ float bf2f(unsigned short h) {
    union { unsigned u; float f; } v; v.u = (unsigned)h << 16;
    return v.f;
}
__device__ __forceinline__ unsigned short f2h(float x) {
    union { _Float16 h; unsigned short s; } c; c.h = (_Float16)x; return c.s;
}
__device__ __forceinline__ float h2f(unsigned short u) {
    union { unsigned short s; _Float16 h; } c; c.s = u; return (float)c.h;
}

// ---- prep: gn partial sums (512 blk) + weight repack (480 blk) ----
__global__ __launch_bounds__(256) void prep_kernel(const float* __restrict__ x,
    float2* __restrict__ partials,
    const float* __restrict__ cw, const float* __restrict__ qw,
    const float* __restrict__ kw_, const float* __restrict__ vw,
    unsigned short* __restrict__ wch, unsigned short* __restrict__ wcl,
    unsigned short* __restrict__ wqh, unsigned short* __restrict__ wql)
{
    int bid = blockIdx.x, tid = threadIdx.x;
    if (bid < 512) {                         // GN partial sums
        size_t base = (size_t)(bid >> 4) * 36864 + (size_t)(bid & 15) * 2304;
        float s = 0.f, s2 = 0.f;
        #pragma unroll
        for (int i = 0; i < 9; ++i) {
            float v = x[base + i * 256 + tid];
            s += v; s2 += v * v;
        }
        #pragma unroll
        for (int d = 1; d < 64; d <<= 1) {
            s  += __shfl_xor(s, d);
            s2 += __shfl_xor(s2, d);
        }
        __shared__ float as[4], as2[4];
        int wid = tid >> 6, lane = tid & 63;
        if (lane == 0) { as[wid] = s; as2[wid] = s2; }
        __syncthreads();
        if (tid == 0) {
            float2 r = { as[0]+as[1]+as[2]+as[3], as2[0]+as2[1]+as2[2]+as2[3] };
            partials[bid] = r;
        }
    } else {                                 // weight repack
        int t = (bid - 512) * 256 + tid;     // < 122880
        if (t < 73728) {
            int e = t & 7, l = (t >> 3) & 63, fr = (t >> 9) & 1;
            int ocg = (t >> 10) & 3, s2 = t >> 12;      // 0..17
            int s = s2 >> 1, ch = s2 & 1;
            int oc = ocg * 32 + fr * 16 + (l & 15);
            int c  = ch * 32 + (l >> 4) * 8 + e;
            float v = cw[oc * 576 + c * 9 + s];
            unsigned short hi = f2bf(v);
            wch[t] = hi; wcl[t] = f2bf(v - bf2f(hi));
        } else {
            int t2 = t - 73728;              // < 49152
            int e = t2 & 7, l = (t2 >> 3) & 63, fr = (t2 >> 9) & 1;
            int ocg = (t2 >> 10) & 3, kc2 = (t2 >> 12) & 3, m = t2 >> 14;
            int oc = ocg * 32 + fr * 16 + (l & 15);
            int c  = kc2 * 32 + (l >> 4) * 8 + e;
            const float* W = (m == 0) ? qw : (m == 1) ? kw_ : vw;
            float v = W[oc * 128 + c];
            unsigned short hi = f2bf(v);
            wqh[t2] = hi; wql[t2] = f2bf(v - bf2f(hi));
        }
    }
}

#define MFMA3(ACC, AH, AL, BH, BL) \
    ACC = __builtin_amdgcn_mfma_f32_16x16x32_bf16(AL, BH, ACC, 0, 0, 0); \
    ACC = __builtin_amdgcn_mfma_f32_16x16x32_bf16(AH, BL, ACC, 0, 0, 0); \
    ACC = __builtin_amdgcn_mfma_f32_16x16x32_bf16(AH, BH, ACC, 0, 0, 0);

// --- fused MFMA (bf16x3): GN-apply + 3x3 conv + GELU + QKV; 256 thr ---
// block = 4x8 pos x 128 oc; wave = 32 pos x 32 oc (2x2 frags)  [r13 structure]
__global__ __launch_bounds__(256) void convqkv_kernel(
    const float* __restrict__ x, const float2* __restrict__ partials,
    const float* __restrict__ gw, const float* __restrict__ gb,
    const unsigned short* __restrict__ wch, const unsigned short* __restrict__ wcl,
    const float* __restrict__ cb,
    const unsigned short* __restrict__ wqh, const unsigned short* __restrict__ wql,
    const float* __restrict__ qbias, const float* __restrict__ kbias,
    const float* __restrict__ vbias,
    float* __restrict__ qo, unsigned short* __restrict__ ko,
    unsigned short* __restrict__ vo)
{
    __shared__ __align__(16) short ph_s[3840];   // [6r][10c][64ch] swizzled, hi
    __shared__ __align__(16) short pl_s[3840];   // lo
    __shared__ __align__(16) short fh_s[4096];   // [32 pos][128 c] swizzled, hi
    __shared__ __align__(16) short fl_s[4096];   // lo
    __shared__ float sgld[32];                   // 16 groups x {mean, rstd}
    int bid = blockIdx.x;
    int swz = (bid & 7) * 72 + (bid >> 3);   // 576 = 8*72, bijective
    int b = swz / 288, rem = swz - b * 288;
    int ty = rem / 12, tx = rem - ty * 12;
    int y0 = ty * 4, x0 = tx * 8;
    int tid = threadIdx.x;

    // issue raw-x loads for the 6x10x64 patch (position-fastest: 40B segments)
    float raw[15];
    #pragma unroll
    for (int it = 0; it < 15; ++it) {
        int idx = it * 256 + tid;            // 3840
        int c = idx / 60, p = idx - c * 60;
        int row = p / 10, col = p - row * 10;
        int gy = y0 - 1 + row, gx = x0 - 1 + col;
        float v = 0.f;
        if ((unsigned)gy < 96u && (unsigned)gx < 96u)
            v = x[((size_t)(b * CIN + c)) * HW + gy * Ww + gx];
        raw[it] = v;
    }

    {                                        // finalize this batch's 16 groups
        float2 pv = partials[b * 256 + tid];
        float s = pv.x, s2 = pv.y;
        #pragma unroll
        for (int d = 1; d < 16; d <<= 1) {
            s  += __shfl_xor(s, d);
            s2 += __shfl_xor(s2, d);
        }
        if ((tid & 15) == 0) {
            const float invN = 1.f / 36864.f;
            float mean = s * invN;
            float var  = s2 * invN - mean * mean;
            sgld[(tid >> 4) * 2]     = mean;
            sgld[(tid >> 4) * 2 + 1] = rsqrtf(var + 1e-5f);
        }
    }
    __syncthreads();

    #pragma unroll
    for (int it = 0; it < 15; ++it) {        // GN (in-bounds only) -> swizzled LDS
        int idx = it * 256 + tid;
        int c = idx / 60, p = idx - c * 60;
        int row = p / 10, col = p - row * 10;
        int gy = y0 - 1 + row, gx = x0 - 1 + col;
        bool ok = ((unsigned)gy < 96u && (unsigned)gx < 96u);
        float val = ok ? ((raw[it] - sgld[(c >> 2) * 2]) * sgld[(c >> 2) * 2 + 1]
                          * gw[c] + gb[c]) : 0.f;     // pad-with-0 is POST-GN
        unsigned short hi = f2bf(val);
        unsigned short lo = f2bf(val - bf2f(hi));
        int di = ((row * 10 + col) << 6) + ((((c >> 3) ^ (col & 7)) << 3) | (c & 7));
        ph_s[di] = (short)hi;
        pl_s[di] = (short)lo;
    }
    __syncthreads();

    int ocg = tid >> 6, l = tid & 63;
    int l15 = l & 15, l4 = l >> 4;
    int oc0 = ocg * 32;
    int p0 = l15, p1 = 16 + l15;
    int r0 = p0 >> 3, xc = p0 & 7;           // p1: rows r0+2, same xc

    f32x4 c00 = {0.f,0.f,0.f,0.f}, c01 = {0.f,0.f,0.f,0.f};
    f32x4 c10 = {0.f,0.f,0.f,0.f}, c11 = {0.f,0.f,0.f,0.f};

    #pragma unroll 3
    for (int s = 0; s < 9; ++s) {
        int dy = s / 3, dx = s - dy * 3;
        int colA = xc + dx, cswz = (colA & 7) << 3;
        #pragma unroll
        for (int ch = 0; ch < 2; ++ch) {
            int gr = (ch * 4 + l4) << 3;
            int ai0 = (((r0 + dy) * 10 + colA) << 6) + (gr ^ cswz);
            int ai1 = (((r0 + 2 + dy) * 10 + colA) << 6) + (gr ^ cswz);
            short8 a0h = *(const short8*)&ph_s[ai0];
            short8 a0l = *(const short8*)&pl_s[ai0];
            short8 a1h = *(const short8*)&ph_s[ai1];
            short8 a1l = *(const short8*)&pl_s[ai1];
            int s2 = s * 2 + ch;
            int wb = ((s2 * 4 + ocg) * 2) * 512 + l * 8;
            short8 b0h = *(const short8*)(wch + wb);
            short8 b0l = *(const short8*)(wcl + wb);
            short8 b1h = *(const short8*)(wch + wb + 512);
            short8 b1l = *(const short8*)(wcl + wb + 512);
            MFMA3(c00, a0h, a0l, b0h, b0l)
            MFMA3(c01, a0h, a0l, b1h, b1l)
            MFMA3(c10, a1h, a1l, b0h, b0l)
            MFMA3(c11, a1h, a1l, b1h, b1l)
        }
    }

    // bias + exact GELU -> hi/lo bf16 -> swizzled f LDS
    float bias0 = cb[oc0 + l15], bias1 = cb[oc0 + 16 + l15];
    #pragma unroll
    for (int mf = 0; mf < 2; ++mf) {
        #pragma unroll
        for (int nf = 0; nf < 2; ++nf) {
            f32x4 a = (mf == 0) ? (nf == 0 ? c00 : c01) : (nf == 0 ? c10 : c11);
            float bs = nf == 0 ? bias0 : bias1;
            int oc = oc0 + nf * 16 + l15;
            #pragma unroll
            for (int rr = 0; rr < 4; ++rr) {
                int p = mf * 16 + l4 * 4 + rr;
                float v = a[rr] + bs;
                float g = 0.5f * v * (1.f + erff(v * 0.70710678118654752f));
                unsigned short hi = f2bf(g);
                unsigned short lo = f2bf(g - bf2f(hi));
                int di = p * 128 + ((((oc >> 3) ^ (p & 7)) << 3) | (oc & 7));
                fh_s[di] = (short)hi;
                fl_s[di] = (short)lo;
            }
        }
    }
    __syncthreads();

    // ---- QKV GEMM: A reloaded from LDS per m (caps VGPR), B = repacked wq ----
    int sw0 = (p0 & 7) << 3, sw1 = (p1 & 7) << 3;
    #pragma unroll 1
    for (int m = 0; m < 3; ++m) {
        const float* Bi = (m == 0) ? qbias : (m == 1) ? kbias : vbias;
        f32x4 d00 = {0.f,0.f,0.f,0.f}, d01 = {0.f,0.f,0.f,0.f};
        f32x4 d10 = {0.f,0.f,0.f,0.f}, d11 = {0.f,0.f,0.f,0.f};
        #pragma unroll
        for (int kc2 = 0; kc2 < 4; ++kc2) {
            int gr2 = (kc2 * 4 + l4) << 3;
            int i0 = p0 * 128 + (gr2 ^ sw0);
            int i1 = p1 * 128 + (gr2 ^ sw1);
            short8 ah0 = *(const short8*)&fh_s[i0];
            short8 al0 = *(const short8*)&fl_s[i0];
            short8 ah1 = *(const short8*)&fh_s[i1];
            short8 al1 = *(const short8*)&fl_s[i1];
            int wb = (((m * 4 + kc2) * 4 + ocg) * 2) * 512 + l * 8;
            short8 b0h = *(const short8*)(wqh + wb);
            short8 b0l = *(const short8*)(wql + wb);
            short8 b1h = *(const short8*)(wqh + wb + 512);
            short8 b1l = *(const short8*)(wql + wb + 512);
            MFMA3(d00, ah0, al0, b0h, b0l)
            MFMA3(d01, ah0, al0, b1h, b1l)
            MFMA3(d10, ah1, al1, b0h, b0l)
            MFMA3(d11, ah1, al1, b1h, b1l)
        }
        float bm0 = Bi[oc0 + l15], bm1 = Bi[oc0 + 16 + l15];
        #pragma unroll
        for (int mf = 0; mf < 2; ++mf) {
            #pragma unroll
            for (int nf = 0; nf < 2; ++nf) {
                f32x4 a = (mf == 0) ? (nf == 0 ? d00 : d01) : (nf == 0 ? d10 : d11);
                float bs = nf == 0 ? bm0 : bm1;
                int oc = oc0 + nf * 16 + l15;
                #pragma unroll
                for (int rr = 0; rr < 4; ++rr) {
                    int p = mf * 16 + l4 * 4 + rr;
                    int yy = y0 + (p >> 3), xx = x0 + (p & 7);
                    size_t gp = ((size_t)(b * HW + yy * Ww + xx)) * CMID + oc;
                    float outv = a[rr] + bs;
                    if (m == 0)      qo[gp] = outv;          // q fp32
                    else if (m == 1) ko[gp] = f2h(outv);     // k fp16
                    else             vo[gp] = f2bf(outv);    // v bf16
                }
            }
        }
    }
}

// ---- 7x7 NAT: block = 4x4 queries; K-union (10x10) fp16 in LDS (25.6KB) ----
// fp16 K: LDS halves -> occupancy cap 12->16 waves/CU; staging traffic -50%
__global__ __launch_bounds__(256) void nat_kernel(const float* __restrict__ q,
    const unsigned short* __restrict__ k, const unsigned short* __restrict__ v,
    float* __restrict__ out)
{
    __shared__ __align__(16) unsigned short Klh[12800];  // 100 rows x 128 ch fp16
    int bid = blockIdx.x;
    int swz = (bid & 7) * 144 + (bid >> 3);  // 1152 = 8*144, bijective
    int b = swz / 576, rem = swz - b * 576;
    int ti = rem / 24, tj = rem - ti * 24;
    int i0 = ti * 4, j0 = tj * 4;
    int ui = i0 - 3; ui = ui < 0 ? 0 : (ui > 86 ? 86 : ui);
    int uj = j0 - 3; uj = uj < 0 ? 0 : (uj > 86 ? 86 : uj);
    int tid = threadIdx.x;

    // stage K union: 100 rows x 32 ushort4 (8B granules), rotation swizzle
    const ushort4* ksrc = (const ushort4*)k;
    ushort4* Kl4 = (ushort4*)Klh;
    #pragma unroll
    for (int it = 0; it < 13; ++it) {
        int idx = it * 256 + tid;
        if (idx < 3200) {
            int row = idx >> 5, c4 = idx & 31;
            int ur = row / 10, uc = row - ur * 10;
            size_t gp = ((size_t)(b * HW + (ui + ur) * Ww + (uj + uc))) * 32 + c4;
            Kl4[row * 32 + ((c4 + row) & 31)] = ksrc[gp];
        }
    }
    __syncthreads();

    int wid = tid >> 6, lane = tid & 63;
    int gy = wid >> 1, gx = wid & 1;
    int iq0 = i0 + 2 * gy, jq0 = j0 + 2 * gx;

    int si0 = iq0 - 3; si0 = si0 < 0 ? 0 : (si0 > 89 ? 89 : si0);
    int si1 = iq0 - 2; si1 = si1 < 0 ? 0 : (si1 > 89 ? 89 : si1);
    int sj0 = jq0 - 3; sj0 = sj0 < 0 ? 0 : (sj0 > 89 ? 89 : sj0);
    int sj1 = jq0 - 2; sj1 = sj1 < 0 ? 0 : (sj1 > 89 ? 89 : sj1);
    int gsi = si0 > 88 ? 88 : si0;
    int gsj = sj0 > 88 ? 88 : sj0;
    int oi0 = si0 - gsi, oi1 = si1 - gsi, oj0 = sj0 - gsj, oj1 = sj1 - gsj;
    int goi = gsi - ui, goj = gsj - uj;      // 0..2 within the 10x10 union

    int wr = lane >> 3, wc = lane & 7;
    int R = (goi + wr) * 10 + (goj + wc);
    int Rs = R * 32;

    // ---- prefetch ALL 64 V values to registers (issue-early / use-late) ----
    int base2 = b * HW + gsi * Ww + gsj;
    const ushort2* vbase = (const ushort2*)(v + (size_t)base2 * CMID);
    ushort2 vpre[64];
    #pragma unroll
    for (int w = 0; w < 64; ++w)
        vpre[w] = vbase[((w >> 3) * Ww + (w & 7)) * 64 + lane];

    // QK: lane's fp16 K row from LDS vs the group's 4 queries (scalar s_loads)
    int qoff = __builtin_amdgcn_readfirstlane((b * HW + iq0 * Ww + jq0) * CMID);
    const float4* qp0 = (const float4*)(q + qoff);
    float a0 = 0.f, a1 = 0.f, a2 = 0.f, a3 = 0.f;
    #pragma unroll 8
    for (int c = 0; c < 32; ++c) {
        ushort4 kv4 = Kl4[Rs + ((c + R) & 31)];
        float kx = h2f(kv4.x), ky = h2f(kv4.y), kz = h2f(kv4.z), kw = h2f(kv4.w);
        float4 q0 = qp0[c], q1 = qp0[c + 32], q2 = qp0[c + 3072], q3 = qp0[c + 3104];
        a0 = fmaf(q0.x, kx, a0); a0 = fmaf(q0.y, ky, a0);
        a0 = fmaf(q0.z, kz, a0); a0 = fmaf(q0.w, kw, a0);
        a1 = fmaf(q1.x, kx, a1); a1 = fmaf(q1.y, ky, a1);
        a1 = fmaf(q1.z, kz, a1); a1 = fmaf(q1.w, kw, a1);
        a2 = fmaf(q2.x, kx, a2); a2 = fmaf(q2.y, ky, a2);
        a2 = fmaf(q2.z, kz, a2); a2 = fmaf(q2.w, kw, a2);
        a3 = fmaf(q3.x, kx, a3); a3 = fmaf(q3.y, ky, a3);
        a3 = fmaf(q3.z, kz, a3); a3 = fmaf(q3.w, kw, a3);
    }

    float l0 = ((unsigned)(wr - oi0) <= 6u && (unsigned)(wc - oj0) <= 6u) ? a0 * NAT_SCALE : -INFINITY;
    float l1 = ((unsigned)(wr - oi0) <= 6u && (unsigned)(wc - oj1) <= 6u) ? a1 * NAT_SCALE : -INFINITY;
    float l2 = ((unsigned)(wr - oi1) <= 6u && (unsigned)(wc - oj0) <= 6u) ? a2 * NAT_SCALE : -INFINITY;
    float l3 = ((unsigned)(wr - oi1) <= 6u && (unsigned)(wc - oj1) <= 6u) ? a3 * NAT_SCALE : -INFINITY;
    float m0 = l0, m1 = l1, m2 = l2, m3 = l3;
    #pragma unroll
    for (int d = 1; d < 64; d <<= 1) {
        m0 = fmaxf(m0, __shfl_xor(m0, d)); m1 = fmaxf(m1, __shfl_xor(m1, d));
        m2 = fmaxf(m2, __shfl_xor(m2, d)); m3 = fmaxf(m3, __shfl_xor(m3, d));
    }
    float e0 = __expf(l0 - m0), e1 = __expf(l1 - m1);
    float e2 = __expf(l2 - m2), e3 = __expf(l3 - m3);
    float s0 = e0, s1 = e1, s2 = e2, s3 = e3;
    #pragma unroll
    for (int d = 1; d < 64; d <<= 1) {
        s0 += __shfl_xor(s0, d); s1 += __shfl_xor(s1, d);
        s2 += __shfl_xor(s2, d); s3 += __shfl_xor(s3, d);
    }
    float w0 = e0 / s0, w1 = e1 / s1, w2 = e2 / s2, w3 = e3 / s3;

    // PV over the group's 8x8 window rows; V already in registers
    float2 o0 = {0.f, 0.f}, o1 = {0.f, 0.f}, o2 = {0.f, 0.f}, o3 = {0.f, 0.f};
    #pragma unroll
    for (int w = 0; w < 64; ++w) {
        ushort2 vraw = vpre[w];
        float vx = bf2f(vraw.x), vy = bf2f(vraw.y);
        float b0 = __shfl(w0, w), b1 = __shfl(w1, w);
        float b2 = __shfl(w2, w), b3 = __shfl(w3, w);
        o0.x = fmaf(b0, vx, o0.x); o0.y = fmaf(b0, vy, o0.y);
        o1.x = fmaf(b1, vx, o1.x); o1.y = fmaf(b1, vy, o1.y);
        o2.x = fmaf(b2, vx, o2.x); o2.y = fmaf(b2, vy, o2.y);
        o3.x = fmaf(b3, vx, o3.x); o3.y = fmaf(b3, vy, o3.y);
    }

    size_t ob = ((size_t)(b * CMID + 2 * lane)) * HW + iq0 * Ww + jq0;
    float2 r0 = {o0.x, o1.x}, r1 = {o0.y, o1.y};
    float2 r2 = {o2.x, o3.x}, r3 = {o2.y, o3.y};
    *(float2*)(out + ob)           = r0;
    *(float2*)(out + ob + HW)      = r1;
    *(float2*)(out + ob + Ww)      = r2;
    *(float2*)(out + ob + HW + Ww) = r3;
}

extern "C" void kernel_launch(void* const* d_in, const int* in_sizes, int n_in,
                              void* d_out, int out_size, void* d_ws, size_t ws_size,
                              hipStream_t stream) {
    const float* x      = (const float*)d_in[0];
    const float* gn_w   = (const float*)d_in[1];
    const float* gn_b   = (const float*)d_in[2];
    const float* conv_w = (const float*)d_in[3];
    const float* conv_b = (const float*)d_in[4];
    const float* q_w    = (const float*)d_in[5];
    const float* q_b    = (const float*)d_in[6];
    const float* k_w    = (const float*)d_in[7];
    const float* k_b    = (const float*)d_in[8];
    const float* v_w    = (const float*)d_in[9];
    const float* v_b    = (const float*)d_in[10];

    float* ws    = (float*)d_ws;
    float2* partials = (float2*)ws;                    // 512 float2
    float* qb_   = ws + 1024;                          // 2,359,296 fp32 (q)
    unsigned short* kbh = (unsigned short*)(qb_ + (size_t)2 * CMID * HW); // fp16 k
    unsigned short* vbh = kbh + (size_t)2 * CMID * HW;                    // bf16 v
    unsigned short* wch = vbh + (size_t)2 * CMID * HW;  // 73,728 each
    unsigned short* wcl = wch + 73728;
    unsigned short* wqh = wcl + 73728;                  // 49,152 each
    unsigned short* wql = wqh + 49152;

    prep_kernel<<<992, 256, 0, stream>>>(x, partials, conv_w, q_w, k_w, v_w,
                                         wch, wcl, wqh, wql);
    convqkv_kernel<<<576, 256, 0, stream>>>(x, partials, gn_w, gn_b,
                                            wch, wcl, conv_b,
                                            wqh, wql, q_b, k_b, v_b,
                                            qb_, kbh, vbh);
    nat_kernel<<<1152, 256, 0, stream>>>(qb_, kbh, vbh, (float*)d_out);
}

// Round 23
// 69.126 us; speedup vs baseline: 1.1585x; 1.1585x over previous
//
#include <hip/hip_runtime.h>
#include <math.h>

#define Hh 96
#define Ww 96
#define HW 9216
#define CIN 64
#define CMID 128
#define NAT_SCALE 11.313708498984761f   // sqrt(128), multiplies logits

typedef __attribute__((ext_vector_type(4))) float f32x4;
typedef __attribute__((ext_vector_type(8))) short short8;

__device__ __forceinline__ unsigned short f2bf(float x) {
    union { float f; unsigned u; } v; v.f = x;
    unsigned r = v.u + 0x7FFF + ((v.u >> 16) & 1);     // RNE
    return (unsigned short)(r >> 16);
}
__device__ __forceinline__ float bf2f(unsigned short h) {
    union { unsigned u; float f; } v; v.u = (unsigned)h << 16;
    return v.f;
}

// ---- prep: gn partial sums (512 blk) + weight repack (480 blk) ----
__global__ __launch_bounds__(256) void prep_kernel(const float* __restrict__ x,
    float2* __restrict__ partials,
    const float* __restrict__ cw, const float* __restrict__ qw,
    const float* __restrict__ kw_, const float* __restrict__ vw,
    unsigned short* __restrict__ wch, unsigned short* __restrict__ wcl,
    unsigned short* __restrict__ wqh, unsigned short* __restrict__ wql)
{
    int bid = blockIdx.x, tid = threadIdx.x;
    if (bid < 512) {                         // GN partial sums
        size_t base = (size_t)(bid >> 4) * 36864 + (size_t)(bid & 15) * 2304;
        float s = 0.f, s2 = 0.f;
        #pragma unroll
        for (int i = 0; i < 9; ++i) {
            float v = x[base + i * 256 + tid];
            s += v; s2 += v * v;
        }
        #pragma unroll
        for (int d = 1; d < 64; d <<= 1) {
            s  += __shfl_xor(s, d);
            s2 += __shfl_xor(s2, d);
        }
        __shared__ float as[4], as2[4];
        int wid = tid >> 6, lane = tid & 63;
        if (lane == 0) { as[wid] = s; as2[wid] = s2; }
        __syncthreads();
        if (tid == 0) {
            float2 r = { as[0]+as[1]+as[2]+as[3], as2[0]+as2[1]+as2[2]+as2[3] };
            partials[bid] = r;
        }
    } else {                                 // weight repack
        int t = (bid - 512) * 256 + tid;     // < 122880
        if (t < 73728) {
            int e = t & 7, l = (t >> 3) & 63, fr = (t >> 9) & 1;
            int ocg = (t >> 10) & 3, s2 = t >> 12;      // 0..17
            int s = s2 >> 1, ch = s2 & 1;
            int oc = ocg * 32 + fr * 16 + (l & 15);
            int c  = ch * 32 + (l >> 4) * 8 + e;
            float v = cw[oc * 576 + c * 9 + s];
            unsigned short hi = f2bf(v);
            wch[t] = hi; wcl[t] = f2bf(v - bf2f(hi));
        } else {
            int t2 = t - 73728;              // < 49152
            int e = t2 & 7, l = (t2 >> 3) & 63, fr = (t2 >> 9) & 1;
            int ocg = (t2 >> 10) & 3, kc2 = (t2 >> 12) & 3, m = t2 >> 14;
            int oc = ocg * 32 + fr * 16 + (l & 15);
            int c  = kc2 * 32 + (l >> 4) * 8 + e;
            const float* W = (m == 0) ? qw : (m == 1) ? kw_ : vw;
            float v = W[oc * 128 + c];
            unsigned short hi = f2bf(v);
            wqh[t2] = hi; wql[t2] = f2bf(v - bf2f(hi));
        }
    }
}

#define MFMA3(ACC, AH, AL, BH, BL) \
    ACC = __builtin_amdgcn_mfma_f32_16x16x32_bf16(AL, BH, ACC, 0, 0, 0); \
    ACC = __builtin_amdgcn_mfma_f32_16x16x32_bf16(AH, BL, ACC, 0, 0, 0); \
    ACC = __builtin_amdgcn_mfma_f32_16x16x32_bf16(AH, BH, ACC, 0, 0, 0);

// --- fused MFMA (bf16x3): GN-apply + 3x3 conv + GELU + QKV; 256 thr ---
// block = 4x8 pos x 128 oc; wave = 32 pos x 32 oc (2x2 frags)  [r13 structure]
__global__ __launch_bounds__(256) void convqkv_kernel(
    const float* __restrict__ x, const float2* __restrict__ partials,
    const float* __restrict__ gw, const float* __restrict__ gb,
    const unsigned short* __restrict__ wch, const unsigned short* __restrict__ wcl,
    const float* __restrict__ cb,
    const unsigned short* __restrict__ wqh, const unsigned short* __restrict__ wql,
    const float* __restrict__ qbias, const float* __restrict__ kbias,
    const float* __restrict__ vbias,
    float* __restrict__ qo, float* __restrict__ ko,
    unsigned short* __restrict__ vo)
{
    __shared__ __align__(16) short ph_s[3840];   // [6r][10c][64ch] swizzled, hi
    __shared__ __align__(16) short pl_s[3840];   // lo
    __shared__ __align__(16) short fh_s[4096];   // [32 pos][128 c] swizzled, hi
    __shared__ __align__(16) short fl_s[4096];   // lo
    __shared__ float sgld[32];                   // 16 groups x {mean, rstd}
    int bid = blockIdx.x;
    int swz = (bid & 7) * 72 + (bid >> 3);   // 576 = 8*72, bijective
    int b = swz / 288, rem = swz - b * 288;
    int ty = rem / 12, tx = rem - ty * 12;
    int y0 = ty * 4, x0 = tx * 8;
    int tid = threadIdx.x;

    // issue raw-x loads for the 6x10x64 patch (position-fastest: 40B segments)
    float raw[15];
    #pragma unroll
    for (int it = 0; it < 15; ++it) {
        int idx = it * 256 + tid;            // 3840
        int c = idx / 60, p = idx - c * 60;
        int row = p / 10, col = p - row * 10;
        int gy = y0 - 1 + row, gx = x0 - 1 + col;
        float v = 0.f;
        if ((unsigned)gy < 96u && (unsigned)gx < 96u)
            v = x[((size_t)(b * CIN + c)) * HW + gy * Ww + gx];
        raw[it] = v;
    }

    {                                        // finalize this batch's 16 groups
        float2 pv = partials[b * 256 + tid];
        float s = pv.x, s2 = pv.y;
        #pragma unroll
        for (int d = 1; d < 16; d <<= 1) {
            s  += __shfl_xor(s, d);
            s2 += __shfl_xor(s2, d);
        }
        if ((tid & 15) == 0) {
            const float invN = 1.f / 36864.f;
            float mean = s * invN;
            float var  = s2 * invN - mean * mean;
            sgld[(tid >> 4) * 2]     = mean;
            sgld[(tid >> 4) * 2 + 1] = rsqrtf(var + 1e-5f);
        }
    }
    __syncthreads();

    #pragma unroll
    for (int it = 0; it < 15; ++it) {        // GN (in-bounds only) -> swizzled LDS
        int idx = it * 256 + tid;
        int c = idx / 60, p = idx - c * 60;
        int row = p / 10, col = p - row * 10;
        int gy = y0 - 1 + row, gx = x0 - 1 + col;
        bool ok = ((unsigned)gy < 96u && (unsigned)gx < 96u);
        float val = ok ? ((raw[it] - sgld[(c >> 2) * 2]) * sgld[(c >> 2) * 2 + 1]
                          * gw[c] + gb[c]) : 0.f;     // pad-with-0 is POST-GN
        unsigned short hi = f2bf(val);
        unsigned short lo = f2bf(val - bf2f(hi));
        int di = ((row * 10 + col) << 6) + ((((c >> 3) ^ (col & 7)) << 3) | (c & 7));
        ph_s[di] = (short)hi;
        pl_s[di] = (short)lo;
    }
    __syncthreads();

    int ocg = tid >> 6, l = tid & 63;
    int l15 = l & 15, l4 = l >> 4;
    int oc0 = ocg * 32;
    int p0 = l15, p1 = 16 + l15;
    int r0 = p0 >> 3, xc = p0 & 7;           // p1: rows r0+2, same xc

    f32x4 c00 = {0.f,0.f,0.f,0.f}, c01 = {0.f,0.f,0.f,0.f};
    f32x4 c10 = {0.f,0.f,0.f,0.f}, c11 = {0.f,0.f,0.f,0.f};

    #pragma unroll 3
    for (int s = 0; s < 9; ++s) {
        int dy = s / 3, dx = s - dy * 3;
        int colA = xc + dx, cswz = (colA & 7) << 3;
        #pragma unroll
        for (int ch = 0; ch < 2; ++ch) {
            int gr = (ch * 4 + l4) << 3;
            int ai0 = (((r0 + dy) * 10 + colA) << 6) + (gr ^ cswz);
            int ai1 = (((r0 + 2 + dy) * 10 + colA) << 6) + (gr ^ cswz);
            short8 a0h = *(const short8*)&ph_s[ai0];
            short8 a0l = *(const short8*)&pl_s[ai0];
            short8 a1h = *(const short8*)&ph_s[ai1];
            short8 a1l = *(const short8*)&pl_s[ai1];
            int s2 = s * 2 + ch;
            int wb = ((s2 * 4 + ocg) * 2) * 512 + l * 8;
            short8 b0h = *(const short8*)(wch + wb);
            short8 b0l = *(const short8*)(wcl + wb);
            short8 b1h = *(const short8*)(wch + wb + 512);
            short8 b1l = *(const short8*)(wcl + wb + 512);
            MFMA3(c00, a0h, a0l, b0h, b0l)
            MFMA3(c01, a0h, a0l, b1h, b1l)
            MFMA3(c10, a1h, a1l, b0h, b0l)
            MFMA3(c11, a1h, a1l, b1h, b1l)
        }
    }

    // bias + exact GELU -> hi/lo bf16 -> swizzled f LDS
    float bias0 = cb[oc0 + l15], bias1 = cb[oc0 + 16 + l15];
    #pragma unroll
    for (int mf = 0; mf < 2; ++mf) {
        #pragma unroll
        for (int nf = 0; nf < 2; ++nf) {
            f32x4 a = (mf == 0) ? (nf == 0 ? c00 : c01) : (nf == 0 ? c10 : c11);
            float bs = nf == 0 ? bias0 : bias1;
            int oc = oc0 + nf * 16 + l15;
            #pragma unroll
            for (int rr = 0; rr < 4; ++rr) {
                int p = mf * 16 + l4 * 4 + rr;
                float v = a[rr] + bs;
                float g = 0.5f * v * (1.f + erff(v * 0.70710678118654752f));
                unsigned short hi = f2bf(g);
                unsigned short lo = f2bf(g - bf2f(hi));
                int di = p * 128 + ((((oc >> 3) ^ (p & 7)) << 3) | (oc & 7));
                fh_s[di] = (short)hi;
                fl_s[di] = (short)lo;
            }
        }
    }
    __syncthreads();

    // ---- QKV GEMM: A reloaded from LDS per m (caps VGPR), B = repacked wq ----
    int sw0 = (p0 & 7) << 3, sw1 = (p1 & 7) << 3;
    #pragma unroll 1
    for (int m = 0; m < 3; ++m) {
        float* Om32 = (m == 0) ? qo : ko;
        const float* Bi = (m == 0) ? qbias : (m == 1) ? kbias : vbias;
        f32x4 d00 = {0.f,0.f,0.f,0.f}, d01 = {0.f,0.f,0.f,0.f};
        f32x4 d10 = {0.f,0.f,0.f,0.f}, d11 = {0.f,0.f,0.f,0.f};
        #pragma unroll
        for (int kc2 = 0; kc2 < 4; ++kc2) {
            int gr2 = (kc2 * 4 + l4) << 3;
            int i0 = p0 * 128 + (gr2 ^ sw0);
            int i1 = p1 * 128 + (gr2 ^ sw1);
            short8 ah0 = *(const short8*)&fh_s[i0];
            short8 al0 = *(const short8*)&fl_s[i0];
            short8 ah1 = *(const short8*)&fh_s[i1];
            short8 al1 = *(const short8*)&fl_s[i1];
            int wb = (((m * 4 + kc2) * 4 + ocg) * 2) * 512 + l * 8;
            short8 b0h = *(const short8*)(wqh + wb);
            short8 b0l = *(const short8*)(wql + wb);
            short8 b1h = *(const short8*)(wqh + wb + 512);
            short8 b1l = *(const short8*)(wql + wb + 512);
            MFMA3(d00, ah0, al0, b0h, b0l)
            MFMA3(d01, ah0, al0, b1h, b1l)
            MFMA3(d10, ah1, al1, b0h, b0l)
            MFMA3(d11, ah1, al1, b1h, b1l)
        }
        float bm0 = Bi[oc0 + l15], bm1 = Bi[oc0 + 16 + l15];
        #pragma unroll
        for (int mf = 0; mf < 2; ++mf) {
            #pragma unroll
            for (int nf = 0; nf < 2; ++nf) {
                f32x4 a = (mf == 0) ? (nf == 0 ? d00 : d01) : (nf == 0 ? d10 : d11);
                float bs = nf == 0 ? bm0 : bm1;
                int oc = oc0 + nf * 16 + l15;
                #pragma unroll
                for (int rr = 0; rr < 4; ++rr) {
                    int p = mf * 16 + l4 * 4 + rr;
                    int yy = y0 + (p >> 3), xx = x0 + (p & 7);
                    size_t gp = ((size_t)(b * HW + yy * Ww + xx)) * CMID + oc;
                    float outv = a[rr] + bs;
                    if (m == 2) vo[gp] = f2bf(outv);     // V plane in bf16
                    else        Om32[gp] = outv;
                }
            }
        }
    }
}

// ---- 7x7 NAT: block = 4x4 queries; K-union (10x10) fp32 in LDS ----
// r21 structure + s_setprio(1) around QK FMA (T5: waves at staggered phases)
__global__ __launch_bounds__(256) void nat_kernel(const float* __restrict__ q,
    const float* __restrict__ k, const unsigned short* __restrict__ v,
    float* __restrict__ out)
{
    __shared__ __align__(16) float Kl[12800];    // 100 rows x 128 ch, swizzled
    int bid = blockIdx.x;
    int swz = (bid & 7) * 144 + (bid >> 3);  // 1152 = 8*144, bijective
    int b = swz / 576, rem = swz - b * 576;
    int ti = rem / 24, tj = rem - ti * 24;
    int i0 = ti * 4, j0 = tj * 4;
    int ui = i0 - 3; ui = ui < 0 ? 0 : (ui > 86 ? 86 : ui);
    int uj = j0 - 3; uj = uj < 0 ? 0 : (uj > 86 ? 86 : uj);
    int tid = threadIdx.x;

    // stage K union: 100 rows x 32 float4, rotation swizzle by full row index
    const float4* ksrc = (const float4*)k;
    float4* Kl4 = (float4*)Kl;
    #pragma unroll
    for (int it = 0; it < 13; ++it) {
        int idx = it * 256 + tid;
        if (idx < 3200) {
            int row = idx >> 5, c4 = idx & 31;
            int ur = row / 10, uc = row - ur * 10;
            size_t gp = ((size_t)(b * HW + (ui + ur) * Ww + (uj + uc))) * 32 + c4;
            Kl4[row * 32 + ((c4 + row) & 31)] = ksrc[gp];
        }
    }
    __syncthreads();

    int wid = tid >> 6, lane = tid & 63;
    int gy = wid >> 1, gx = wid & 1;
    int iq0 = i0 + 2 * gy, jq0 = j0 + 2 * gx;

    int si0 = iq0 - 3; si0 = si0 < 0 ? 0 : (si0 > 89 ? 89 : si0);
    int si1 = iq0 - 2; si1 = si1 < 0 ? 0 : (si1 > 89 ? 89 : si1);
    int sj0 = jq0 - 3; sj0 = sj0 < 0 ? 0 : (sj0 > 89 ? 89 : sj0);
    int sj1 = jq0 - 2; sj1 = sj1 < 0 ? 0 : (sj1 > 89 ? 89 : sj1);
    int gsi = si0 > 88 ? 88 : si0;
    int gsj = sj0 > 88 ? 88 : sj0;
    int oi0 = si0 - gsi, oi1 = si1 - gsi, oj0 = sj0 - gsj, oj1 = sj1 - gsj;
    int goi = gsi - ui, goj = gsj - uj;      // 0..2 within the 10x10 union

    int wr = lane >> 3, wc = lane & 7;
    int R = (goi + wr) * 10 + (goj + wc);
    int Rs = R * 32;

    // ---- prefetch ALL 64 V values to registers (issue-early / use-late) ----
    int base2 = b * HW + gsi * Ww + gsj;
    const ushort2* vbase = (const ushort2*)(v + (size_t)base2 * CMID);
    ushort2 vpre[64];
    #pragma unroll
    for (int w = 0; w < 64; ++w)
        vpre[w] = vbase[((w >> 3) * Ww + (w & 7)) * 64 + lane];

    // QK: lane's K row from LDS vs the group's 4 queries (scalar s_loads)
    int qoff = __builtin_amdgcn_readfirstlane((b * HW + iq0 * Ww + jq0) * CMID);
    const float4* qp0 = (const float4*)(q + qoff);
    float a0 = 0.f, a1 = 0.f, a2 = 0.f, a3 = 0.f;
    __builtin_amdgcn_s_setprio(1);
    #pragma unroll 8
    for (int c = 0; c < 32; ++c) {
        float4 kv = Kl4[Rs + ((c + R) & 31)];
        float4 q0 = qp0[c], q1 = qp0[c + 32], q2 = qp0[c + 3072], q3 = qp0[c + 3104];
        a0 = fmaf(q0.x, kv.x, a0); a0 = fmaf(q0.y, kv.y, a0);
        a0 = fmaf(q0.z, kv.z, a0); a0 = fmaf(q0.w, kv.w, a0);
        a1 = fmaf(q1.x, kv.x, a1); a1 = fmaf(q1.y, kv.y, a1);
        a1 = fmaf(q1.z, kv.z, a1); a1 = fmaf(q1.w, kv.w, a1);
        a2 = fmaf(q2.x, kv.x, a2); a2 = fmaf(q2.y, kv.y, a2);
        a2 = fmaf(q2.z, kv.z, a2); a2 = fmaf(q2.w, kv.w, a2);
        a3 = fmaf(q3.x, kv.x, a3); a3 = fmaf(q3.y, kv.y, a3);
        a3 = fmaf(q3.z, kv.z, a3); a3 = fmaf(q3.w, kv.w, a3);
    }
    __builtin_amdgcn_s_setprio(0);

    float l0 = ((unsigned)(wr - oi0) <= 6u && (unsigned)(wc - oj0) <= 6u) ? a0 * NAT_SCALE : -INFINITY;
    float l1 = ((unsigned)(wr - oi0) <= 6u && (unsigned)(wc - oj1) <= 6u) ? a1 * NAT_SCALE : -INFINITY;
    float l2 = ((unsigned)(wr - oi1) <= 6u && (unsigned)(wc - oj0) <= 6u) ? a2 * NAT_SCALE : -INFINITY;
    float l3 = ((unsigned)(wr - oi1) <= 6u && (unsigned)(wc - oj1) <= 6u) ? a3 * NAT_SCALE : -INFINITY;
    float m0 = l0, m1 = l1, m2 = l2, m3 = l3;
    #pragma unroll
    for (int d = 1; d < 64; d <<= 1) {
        m0 = fmaxf(m0, __shfl_xor(m0, d)); m1 = fmaxf(m1, __shfl_xor(m1, d));
        m2 = fmaxf(m2, __shfl_xor(m2, d)); m3 = fmaxf(m3, __shfl_xor(m3, d));
    }
    float e0 = __expf(l0 - m0), e1 = __expf(l1 - m1);
    float e2 = __expf(l2 - m2), e3 = __expf(l3 - m3);
    float s0 = e0, s1 = e1, s2 = e2, s3 = e3;
    #pragma unroll
    for (int d = 1; d < 64; d <<= 1) {
        s0 += __shfl_xor(s0, d); s1 += __shfl_xor(s1, d);
        s2 += __shfl_xor(s2, d); s3 += __shfl_xor(s3, d);
    }
    float w0 = e0 / s0, w1 = e1 / s1, w2 = e2 / s2, w3 = e3 / s3;

    // PV over the group's 8x8 window rows; V already in registers
    float2 o0 = {0.f, 0.f}, o1 = {0.f, 0.f}, o2 = {0.f, 0.f}, o3 = {0.f, 0.f};
    #pragma unroll
    for (int w = 0; w < 64; ++w) {
        ushort2 vraw = vpre[w];
        float vx = bf2f(vraw.x), vy = bf2f(vraw.y);
        float b0 = __shfl(w0, w), b1 = __shfl(w1, w);
        float b2 = __shfl(w2, w), b3 = __shfl(w3, w);
        o0.x = fmaf(b0, vx, o0.x); o0.y = fmaf(b0, vy, o0.y);
        o1.x = fmaf(b1, vx, o1.x); o1.y = fmaf(b1, vy, o1.y);
        o2.x = fmaf(b2, vx, o2.x); o2.y = fmaf(b2, vy, o2.y);
        o3.x = fmaf(b3, vx, o3.x); o3.y = fmaf(b3, vy, o3.y);
    }

    size_t ob = ((size_t)(b * CMID + 2 * lane)) * HW + iq0 * Ww + jq0;
    float2 r0 = {o0.x, o1.x}, r1 = {o0.y, o1.y};
    float2 r2 = {o2.x, o3.x}, r3 = {o2.y, o3.y};
    *(float2*)(out + ob)           = r0;
    *(float2*)(out + ob + HW)      = r1;
    *(float2*)(out + ob + Ww)      = r2;
    *(float2*)(out + ob + HW + Ww) = r3;
}

extern "C" void kernel_launch(void* const* d_in, const int* in_sizes, int n_in,
                              void* d_out, int out_size, void* d_ws, size_t ws_size,
                              hipStream_t stream) {
    const float* x      = (const float*)d_in[0];
    const float* gn_w   = (const float*)d_in[1];
    const float* gn_b   = (const float*)d_in[2];
    const float* conv_w = (const float*)d_in[3];
    const float* conv_b = (const float*)d_in[4];
    const float* q_w    = (const float*)d_in[5];
    const float* q_b    = (const float*)d_in[6];
    const float* k_w    = (const float*)d_in[7];
    const float* k_b    = (const float*)d_in[8];
    const float* v_w    = (const float*)d_in[9];
    const float* v_b    = (const float*)d_in[10];

    float* ws    = (float*)d_ws;
    float2* partials = (float2*)ws;                    // 512 float2
    float* qb_   = ws + 1024;                          // 2 x 2,359,296 fp32 (q,k)
    float* kb_   = qb_ + (size_t)2 * CMID * HW;
    unsigned short* vbh = (unsigned short*)(kb_ + (size_t)2 * CMID * HW); // bf16 v
    unsigned short* wch = vbh + (size_t)2 * CMID * HW;  // 73,728 each
    unsigned short* wcl = wch + 73728;
    unsigned short* wqh = wcl + 73728;                  // 49,152 each
    unsigned short* wql = wqh + 49152;

    prep_kernel<<<992, 256, 0, stream>>>(x, partials, conv_w, q_w, k_w, v_w,
                                         wch, wcl, wqh, wql);
    convqkv_kernel<<<576, 256, 0, stream>>>(x, partials, gn_w, gn_b,
                                            wch, wcl, conv_b,
                                            wqh, wql, q_b, k_b, v_b,
                                            qb_, kb_, vbh);
    nat_kernel<<<1152, 256, 0, stream>>>(qb_, kb_, vbh, (float*)d_out);
}

// Round 24
// 68.586 us; speedup vs baseline: 1.1677x; 1.0079x over previous
//
#include <hip/hip_runtime.h>
#include <math.h>

#define Hh 96
#define Ww 96
#define HW 9216
#define CIN 64
#define CMID 128
#define NAT_SCALE 11.313708498984761f   // sqrt(128), multiplies logits

typedef __attribute__((ext_vector_type(4))) float f32x4;
typedef __attribute__((ext_vector_type(8))) short short8;

__device__ __forceinline__ unsigned short f2bf(float x) {
    union { float f; unsigned u; } v; v.f = x;
    unsigned r = v.u + 0x7FFF + ((v.u >> 16) & 1);     // RNE
    return (unsigned short)(r >> 16);
}
__device__ __forceinline__ float bf2f(unsigned short h) {
    union { unsigned u; float f; } v; v.u = (unsigned)h << 16;
    return v.f;
}

// ---- prep: gn partial sums (512 blk) + weight repack (480 blk) ----
__global__ __launch_bounds__(256) void prep_kernel(const float* __restrict__ x,
    float2* __restrict__ partials,
    const float* __restrict__ cw, const float* __restrict__ qw,
    const float* __restrict__ kw_, const float* __restrict__ vw,
    unsigned short* __restrict__ wch, unsigned short* __restrict__ wcl,
    unsigned short* __restrict__ wqh, unsigned short* __restrict__ wql)
{
    int bid = blockIdx.x, tid = threadIdx.x;
    if (bid < 512) {                         // GN partial sums
        size_t base = (size_t)(bid >> 4) * 36864 + (size_t)(bid & 15) * 2304;
        float s = 0.f, s2 = 0.f;
        #pragma unroll
        for (int i = 0; i < 9; ++i) {
            float v = x[base + i * 256 + tid];
            s += v; s2 += v * v;
        }
        #pragma unroll
        for (int d = 1; d < 64; d <<= 1) {
            s  += __shfl_xor(s, d);
            s2 += __shfl_xor(s2, d);
        }
        __shared__ float as[4], as2[4];
        int wid = tid >> 6, lane = tid & 63;
        if (lane == 0) { as[wid] = s; as2[wid] = s2; }
        __syncthreads();
        if (tid == 0) {
            float2 r = { as[0]+as[1]+as[2]+as[3], as2[0]+as2[1]+as2[2]+as2[3] };
            partials[bid] = r;
        }
    } else {                                 // weight repack
        int t = (bid - 512) * 256 + tid;     // < 122880
        if (t < 73728) {
            int e = t & 7, l = (t >> 3) & 63, fr = (t >> 9) & 1;
            int ocg = (t >> 10) & 3, s2 = t >> 12;      // 0..17
            int s = s2 >> 1, ch = s2 & 1;
            int oc = ocg * 32 + fr * 16 + (l & 15);
            int c  = ch * 32 + (l >> 4) * 8 + e;
            float v = cw[oc * 576 + c * 9 + s];
            unsigned short hi = f2bf(v);
            wch[t] = hi; wcl[t] = f2bf(v - bf2f(hi));
        } else {
            int t2 = t - 73728;              // < 49152
            int e = t2 & 7, l = (t2 >> 3) & 63, fr = (t2 >> 9) & 1;
            int ocg = (t2 >> 10) & 3, kc2 = (t2 >> 12) & 3, m = t2 >> 14;
            int oc = ocg * 32 + fr * 16 + (l & 15);
            int c  = kc2 * 32 + (l >> 4) * 8 + e;
            const float* W = (m == 0) ? qw : (m == 1) ? kw_ : vw;
            float v = W[oc * 128 + c];
            unsigned short hi = f2bf(v);
            wqh[t2] = hi; wql[t2] = f2bf(v - bf2f(hi));
        }
    }
}

#define MFMA3(ACC, AH, AL, BH, BL) \
    ACC = __builtin_amdgcn_mfma_f32_16x16x32_bf16(AL, BH, ACC, 0, 0, 0); \
    ACC = __builtin_amdgcn_mfma_f32_16x16x32_bf16(AH, BL, ACC, 0, 0, 0); \
    ACC = __builtin_amdgcn_mfma_f32_16x16x32_bf16(AH, BH, ACC, 0, 0, 0);

// --- fused MFMA (bf16x3): GN-apply + 3x3 conv + GELU + QKV; 256 thr ---
// block = 4x8 pos x 128 oc; wave = 32 pos x 32 oc (2x2 frags)  [r13 structure]
__global__ __launch_bounds__(256) void convqkv_kernel(
    const float* __restrict__ x, const float2* __restrict__ partials,
    const float* __restrict__ gw, const float* __restrict__ gb,
    const unsigned short* __restrict__ wch, const unsigned short* __restrict__ wcl,
    const float* __restrict__ cb,
    const unsigned short* __restrict__ wqh, const unsigned short* __restrict__ wql,
    const float* __restrict__ qbias, const float* __restrict__ kbias,
    const float* __restrict__ vbias,
    float* __restrict__ qo, float* __restrict__ ko,
    unsigned short* __restrict__ vo)
{
    __shared__ __align__(16) short ph_s[3840];   // [6r][10c][64ch] swizzled, hi
    __shared__ __align__(16) short pl_s[3840];   // lo
    __shared__ __align__(16) short fh_s[4096];   // [32 pos][128 c] swizzled, hi
    __shared__ __align__(16) short fl_s[4096];   // lo
    __shared__ float sgld[32];                   // 16 groups x {mean, rstd}
    int bid = blockIdx.x;
    int swz = (bid & 7) * 72 + (bid >> 3);   // 576 = 8*72, bijective
    int b = swz / 288, rem = swz - b * 288;
    int ty = rem / 12, tx = rem - ty * 12;
    int y0 = ty * 4, x0 = tx * 8;
    int tid = threadIdx.x;

    // issue raw-x loads for the 6x10x64 patch (position-fastest: 40B segments)
    float raw[15];
    #pragma unroll
    for (int it = 0; it < 15; ++it) {
        int idx = it * 256 + tid;            // 3840
        int c = idx / 60, p = idx - c * 60;
        int row = p / 10, col = p - row * 10;
        int gy = y0 - 1 + row, gx = x0 - 1 + col;
        float v = 0.f;
        if ((unsigned)gy < 96u && (unsigned)gx < 96u)
            v = x[((size_t)(b * CIN + c)) * HW + gy * Ww + gx];
        raw[it] = v;
    }

    {                                        // finalize this batch's 16 groups
        float2 pv = partials[b * 256 + tid];
        float s = pv.x, s2 = pv.y;
        #pragma unroll
        for (int d = 1; d < 16; d <<= 1) {
            s  += __shfl_xor(s, d);
            s2 += __shfl_xor(s2, d);
        }
        if ((tid & 15) == 0) {
            const float invN = 1.f / 36864.f;
            float mean = s * invN;
            float var  = s2 * invN - mean * mean;
            sgld[(tid >> 4) * 2]     = mean;
            sgld[(tid >> 4) * 2 + 1] = rsqrtf(var + 1e-5f);
        }
    }
    __syncthreads();

    #pragma unroll
    for (int it = 0; it < 15; ++it) {        // GN (in-bounds only) -> swizzled LDS
        int idx = it * 256 + tid;
        int c = idx / 60, p = idx - c * 60;
        int row = p / 10, col = p - row * 10;
        int gy = y0 - 1 + row, gx = x0 - 1 + col;
        bool ok = ((unsigned)gy < 96u && (unsigned)gx < 96u);
        float val = ok ? ((raw[it] - sgld[(c >> 2) * 2]) * sgld[(c >> 2) * 2 + 1]
                          * gw[c] + gb[c]) : 0.f;     // pad-with-0 is POST-GN
        unsigned short hi = f2bf(val);
        unsigned short lo = f2bf(val - bf2f(hi));
        int di = ((row * 10 + col) << 6) + ((((c >> 3) ^ (col & 7)) << 3) | (c & 7));
        ph_s[di] = (short)hi;
        pl_s[di] = (short)lo;
    }
    __syncthreads();

    int ocg = tid >> 6, l = tid & 63;
    int l15 = l & 15, l4 = l >> 4;
    int oc0 = ocg * 32;
    int p0 = l15, p1 = 16 + l15;
    int r0 = p0 >> 3, xc = p0 & 7;           // p1: rows r0+2, same xc

    f32x4 c00 = {0.f,0.f,0.f,0.f}, c01 = {0.f,0.f,0.f,0.f};
    f32x4 c10 = {0.f,0.f,0.f,0.f}, c11 = {0.f,0.f,0.f,0.f};

    #pragma unroll 3
    for (int s = 0; s < 9; ++s) {
        int dy = s / 3, dx = s - dy * 3;
        int colA = xc + dx, cswz = (colA & 7) << 3;
        #pragma unroll
        for (int ch = 0; ch < 2; ++ch) {
            int gr = (ch * 4 + l4) << 3;
            int ai0 = (((r0 + dy) * 10 + colA) << 6) + (gr ^ cswz);
            int ai1 = (((r0 + 2 + dy) * 10 + colA) << 6) + (gr ^ cswz);
            short8 a0h = *(const short8*)&ph_s[ai0];
            short8 a0l = *(const short8*)&pl_s[ai0];
            short8 a1h = *(const short8*)&ph_s[ai1];
            short8 a1l = *(const short8*)&pl_s[ai1];
            int s2 = s * 2 + ch;
            int wb = ((s2 * 4 + ocg) * 2) * 512 + l * 8;
            short8 b0h = *(const short8*)(wch + wb);
            short8 b0l = *(const short8*)(wcl + wb);
            short8 b1h = *(const short8*)(wch + wb + 512);
            short8 b1l = *(const short8*)(wcl + wb + 512);
            MFMA3(c00, a0h, a0l, b0h, b0l)
            MFMA3(c01, a0h, a0l, b1h, b1l)
            MFMA3(c10, a1h, a1l, b0h, b0l)
            MFMA3(c11, a1h, a1l, b1h, b1l)
        }
    }

    // bias + exact GELU -> hi/lo bf16 -> swizzled f LDS
    float bias0 = cb[oc0 + l15], bias1 = cb[oc0 + 16 + l15];
    #pragma unroll
    for (int mf = 0; mf < 2; ++mf) {
        #pragma unroll
        for (int nf = 0; nf < 2; ++nf) {
            f32x4 a = (mf == 0) ? (nf == 0 ? c00 : c01) : (nf == 0 ? c10 : c11);
            float bs = nf == 0 ? bias0 : bias1;
            int oc = oc0 + nf * 16 + l15;
            #pragma unroll
            for (int rr = 0; rr < 4; ++rr) {
                int p = mf * 16 + l4 * 4 + rr;
                float v = a[rr] + bs;
                float g = 0.5f * v * (1.f + erff(v * 0.70710678118654752f));
                unsigned short hi = f2bf(g);
                unsigned short lo = f2bf(g - bf2f(hi));
                int di = p * 128 + ((((oc >> 3) ^ (p & 7)) << 3) | (oc & 7));
                fh_s[di] = (short)hi;
                fl_s[di] = (short)lo;
            }
        }
    }
    __syncthreads();

    // ---- QKV GEMM: A reloaded from LDS per m (caps VGPR), B = repacked wq ----
    int sw0 = (p0 & 7) << 3, sw1 = (p1 & 7) << 3;
    #pragma unroll 1
    for (int m = 0; m < 3; ++m) {
        float* Om32 = (m == 0) ? qo : ko;
        const float* Bi = (m == 0) ? qbias : (m == 1) ? kbias : vbias;
        f32x4 d00 = {0.f,0.f,0.f,0.f}, d01 = {0.f,0.f,0.f,0.f};
        f32x4 d10 = {0.f,0.f,0.f,0.f}, d11 = {0.f,0.f,0.f,0.f};
        #pragma unroll
        for (int kc2 = 0; kc2 < 4; ++kc2) {
            int gr2 = (kc2 * 4 + l4) << 3;
            int i0 = p0 * 128 + (gr2 ^ sw0);
            int i1 = p1 * 128 + (gr2 ^ sw1);
            short8 ah0 = *(const short8*)&fh_s[i0];
            short8 al0 = *(const short8*)&fl_s[i0];
            short8 ah1 = *(const short8*)&fh_s[i1];
            short8 al1 = *(const short8*)&fl_s[i1];
            int wb = (((m * 4 + kc2) * 4 + ocg) * 2) * 512 + l * 8;
            short8 b0h = *(const short8*)(wqh + wb);
            short8 b0l = *(const short8*)(wql + wb);
            short8 b1h = *(const short8*)(wqh + wb + 512);
            short8 b1l = *(const short8*)(wql + wb + 512);
            MFMA3(d00, ah0, al0, b0h, b0l)
            MFMA3(d01, ah0, al0, b1h, b1l)
            MFMA3(d10, ah1, al1, b0h, b0l)
            MFMA3(d11, ah1, al1, b1h, b1l)
        }
        float bm0 = Bi[oc0 + l15], bm1 = Bi[oc0 + 16 + l15];
        #pragma unroll
        for (int mf = 0; mf < 2; ++mf) {
            #pragma unroll
            for (int nf = 0; nf < 2; ++nf) {
                f32x4 a = (mf == 0) ? (nf == 0 ? d00 : d01) : (nf == 0 ? d10 : d11);
                float bs = nf == 0 ? bm0 : bm1;
                int oc = oc0 + nf * 16 + l15;
                #pragma unroll
                for (int rr = 0; rr < 4; ++rr) {
                    int p = mf * 16 + l4 * 4 + rr;
                    int yy = y0 + (p >> 3), xx = x0 + (p & 7);
                    size_t gp = ((size_t)(b * HW + yy * Ww + xx)) * CMID + oc;
                    float outv = a[rr] + bs;
                    if (m == 2) vo[gp] = f2bf(outv);     // V plane in bf16
                    else        Om32[gp] = outv;
                }
            }
        }
    }
}

// ---- 7x7 NAT: block = 4x4 queries; K-union (10x10) fp32 in LDS ----
// scalar q loads + V register prefetch (r21 = measured best: 68.8us)
__global__ __launch_bounds__(256) void nat_kernel(const float* __restrict__ q,
    const float* __restrict__ k, const unsigned short* __restrict__ v,
    float* __restrict__ out)
{
    __shared__ __align__(16) float Kl[12800];    // 100 rows x 128 ch, swizzled
    int bid = blockIdx.x;
    int swz = (bid & 7) * 144 + (bid >> 3);  // 1152 = 8*144, bijective
    int b = swz / 576, rem = swz - b * 576;
    int ti = rem / 24, tj = rem - ti * 24;
    int i0 = ti * 4, j0 = tj * 4;
    int ui = i0 - 3; ui = ui < 0 ? 0 : (ui > 86 ? 86 : ui);
    int uj = j0 - 3; uj = uj < 0 ? 0 : (uj > 86 ? 86 : uj);
    int tid = threadIdx.x;

    // stage K union: 100 rows x 32 float4, rotation swizzle by full row index
    const float4* ksrc = (const float4*)k;
    float4* Kl4 = (float4*)Kl;
    #pragma unroll
    for (int it = 0; it < 13; ++it) {
        int idx = it * 256 + tid;
        if (idx < 3200) {
            int row = idx >> 5, c4 = idx & 31;
            int ur = row / 10, uc = row - ur * 10;
            size_t gp = ((size_t)(b * HW + (ui + ur) * Ww + (uj + uc))) * 32 + c4;
            Kl4[row * 32 + ((c4 + row) & 31)] = ksrc[gp];
        }
    }
    __syncthreads();

    int wid = tid >> 6, lane = tid & 63;
    int gy = wid >> 1, gx = wid & 1;
    int iq0 = i0 + 2 * gy, jq0 = j0 + 2 * gx;

    int si0 = iq0 - 3; si0 = si0 < 0 ? 0 : (si0 > 89 ? 89 : si0);
    int si1 = iq0 - 2; si1 = si1 < 0 ? 0 : (si1 > 89 ? 89 : si1);
    int sj0 = jq0 - 3; sj0 = sj0 < 0 ? 0 : (sj0 > 89 ? 89 : sj0);
    int sj1 = jq0 - 2; sj1 = sj1 < 0 ? 0 : (sj1 > 89 ? 89 : sj1);
    int gsi = si0 > 88 ? 88 : si0;
    int gsj = sj0 > 88 ? 88 : sj0;
    int oi0 = si0 - gsi, oi1 = si1 - gsi, oj0 = sj0 - gsj, oj1 = sj1 - gsj;
    int goi = gsi - ui, goj = gsj - uj;      // 0..2 within the 10x10 union

    int wr = lane >> 3, wc = lane & 7;
    int R = (goi + wr) * 10 + (goj + wc);
    int Rs = R * 32;

    // ---- prefetch ALL 64 V values to registers (issue-early / use-late) ----
    int base2 = b * HW + gsi * Ww + gsj;
    const ushort2* vbase = (const ushort2*)(v + (size_t)base2 * CMID);
    ushort2 vpre[64];
    #pragma unroll
    for (int w = 0; w < 64; ++w)
        vpre[w] = vbase[((w >> 3) * Ww + (w & 7)) * 64 + lane];

    // QK: lane's K row from LDS vs the group's 4 queries (scalar s_loads)
    int qoff = __builtin_amdgcn_readfirstlane((b * HW + iq0 * Ww + jq0) * CMID);
    const float4* qp0 = (const float4*)(q + qoff);
    float a0 = 0.f, a1 = 0.f, a2 = 0.f, a3 = 0.f;
    #pragma unroll 8
    for (int c = 0; c < 32; ++c) {
        float4 kv = Kl4[Rs + ((c + R) & 31)];
        float4 q0 = qp0[c], q1 = qp0[c + 32], q2 = qp0[c + 3072], q3 = qp0[c + 3104];
        a0 = fmaf(q0.x, kv.x, a0); a0 = fmaf(q0.y, kv.y, a0);
        a0 = fmaf(q0.z, kv.z, a0); a0 = fmaf(q0.w, kv.w, a0);
        a1 = fmaf(q1.x, kv.x, a1); a1 = fmaf(q1.y, kv.y, a1);
        a1 = fmaf(q1.z, kv.z, a1); a1 = fmaf(q1.w, kv.w, a1);
        a2 = fmaf(q2.x, kv.x, a2); a2 = fmaf(q2.y, kv.y, a2);
        a2 = fmaf(q2.z, kv.z, a2); a2 = fmaf(q2.w, kv.w, a2);
        a3 = fmaf(q3.x, kv.x, a3); a3 = fmaf(q3.y, kv.y, a3);
        a3 = fmaf(q3.z, kv.z, a3); a3 = fmaf(q3.w, kv.w, a3);
    }

    float l0 = ((unsigned)(wr - oi0) <= 6u && (unsigned)(wc - oj0) <= 6u) ? a0 * NAT_SCALE : -INFINITY;
    float l1 = ((unsigned)(wr - oi0) <= 6u && (unsigned)(wc - oj1) <= 6u) ? a1 * NAT_SCALE : -INFINITY;
    float l2 = ((unsigned)(wr - oi1) <= 6u && (unsigned)(wc - oj0) <= 6u) ? a2 * NAT_SCALE : -INFINITY;
    float l3 = ((unsigned)(wr - oi1) <= 6u && (unsigned)(wc - oj1) <= 6u) ? a3 * NAT_SCALE : -INFINITY;
    float m0 = l0, m1 = l1, m2 = l2, m3 = l3;
    #pragma unroll
    for (int d = 1; d < 64; d <<= 1) {
        m0 = fmaxf(m0, __shfl_xor(m0, d)); m1 = fmaxf(m1, __shfl_xor(m1, d));
        m2 = fmaxf(m2, __shfl_xor(m2, d)); m3 = fmaxf(m3, __shfl_xor(m3, d));
    }
    float e0 = __expf(l0 - m0), e1 = __expf(l1 - m1);
    float e2 = __expf(l2 - m2), e3 = __expf(l3 - m3);
    float s0 = e0, s1 = e1, s2 = e2, s3 = e3;
    #pragma unroll
    for (int d = 1; d < 64; d <<= 1) {
        s0 += __shfl_xor(s0, d); s1 += __shfl_xor(s1, d);
        s2 += __shfl_xor(s2, d); s3 += __shfl_xor(s3, d);
    }
    float w0 = e0 / s0, w1 = e1 / s1, w2 = e2 / s2, w3 = e3 / s3;

    // PV over the group's 8x8 window rows; V already in registers
    float2 o0 = {0.f, 0.f}, o1 = {0.f, 0.f}, o2 = {0.f, 0.f}, o3 = {0.f, 0.f};
    #pragma unroll
    for (int w = 0; w < 64; ++w) {
        ushort2 vraw = vpre[w];
        float vx = bf2f(vraw.x), vy = bf2f(vraw.y);
        float b0 = __shfl(w0, w), b1 = __shfl(w1, w);
        float b2 = __shfl(w2, w), b3 = __shfl(w3, w);
        o0.x = fmaf(b0, vx, o0.x); o0.y = fmaf(b0, vy, o0.y);
        o1.x = fmaf(b1, vx, o1.x); o1.y = fmaf(b1, vy, o1.y);
        o2.x = fmaf(b2, vx, o2.x); o2.y = fmaf(b2, vy, o2.y);
        o3.x = fmaf(b3, vx, o3.x); o3.y = fmaf(b3, vy, o3.y);
    }

    size_t ob = ((size_t)(b * CMID + 2 * lane)) * HW + iq0 * Ww + jq0;
    float2 r0 = {o0.x, o1.x}, r1 = {o0.y, o1.y};
    float2 r2 = {o2.x, o3.x}, r3 = {o2.y, o3.y};
    *(float2*)(out + ob)           = r0;
    *(float2*)(out + ob + HW)      = r1;
    *(float2*)(out + ob + Ww)      = r2;
    *(float2*)(out + ob + HW + Ww) = r3;
}

extern "C" void kernel_launch(void* const* d_in, const int* in_sizes, int n_in,
                              void* d_out, int out_size, void* d_ws, size_t ws_size,
                              hipStream_t stream) {
    const float* x      = (const float*)d_in[0];
    const float* gn_w   = (const float*)d_in[1];
    const float* gn_b   = (const float*)d_in[2];
    const float* conv_w = (const float*)d_in[3];
    const float* conv_b = (const float*)d_in[4];
    const float* q_w    = (const float*)d_in[5];
    const float* q_b    = (const float*)d_in[6];
    const float* k_w    = (const float*)d_in[7];
    const float* k_b    = (const float*)d_in[8];
    const float* v_w    = (const float*)d_in[9];
    const float* v_b    = (const float*)d_in[10];

    float* ws    = (float*)d_ws;
    float2* partials = (float2*)ws;                    // 512 float2
    float* qb_   = ws + 1024;                          // 2 x 2,359,296 fp32 (q,k)
    float* kb_   = qb_ + (size_t)2 * CMID * HW;
    unsigned short* vbh = (unsigned short*)(kb_ + (size_t)2 * CMID * HW); // bf16 v
    unsigned short* wch = vbh + (size_t)2 * CMID * HW;  // 73,728 each
    unsigned short* wcl = wch + 73728;
    unsigned short* wqh = wcl + 73728;                  // 49,152 each
    unsigned short* wql = wqh + 49152;

    prep_kernel<<<992, 256, 0, stream>>>(x, partials, conv_w, q_w, k_w, v_w,
                                         wch, wcl, wqh, wql);
    convqkv_kernel<<<576, 256, 0, stream>>>(x, partials, gn_w, gn_b,
                                            wch, wcl, conv_b,
                                            wqh, wql, q_b, k_b, v_b,
                                            qb_, kb_, vbh);
    nat_kernel<<<1152, 256, 0, stream>>>(qb_, kb_, vbh, (float*)d_out);
}